// Round 2
// baseline (346.804 us; speedup 1.0000x reference)
//
#include <hip/hip_runtime.h>
#include <hip/hip_bf16.h>

#define NTOK 49
#define NPAD 64
#define CDIM 128
#define C3   384
#define NHEAD 4
#define HDIM 32
#define SCALE 0.17677669529663687f

#define QS 136   // q/k row stride (elems): 272 B rows, bank offset 4 mod 32
#define VS 72    // vT row stride
#define PS 40    // per-wave P row stride (32-col chunks)

typedef __attribute__((ext_vector_type(8))) __bf16 bf16x8;
typedef __attribute__((ext_vector_type(4))) __bf16 bf16x4;
typedef __attribute__((ext_vector_type(4))) float f32x4;

// ws layout (bytes):
//   qkvT  __bf16[384][128]  @ 0        (98304 B)   qkvT[n][k] = qkv_w[k][n]
//   projT __bf16[128][128]  @ 98304    (32768 B)
//   blut  float [4][64][64] @ 131072   (65536 B)   rel-bias LUT, col>=49 -> -1e30

__global__ __launch_bounds__(256) void prep_kernel(
    const float* __restrict__ qkv_w, const float* __restrict__ proj_w,
    const float* __restrict__ bias_table,
    __bf16* __restrict__ qkvT, __bf16* __restrict__ projT, float* __restrict__ blut)
{
  int o = blockIdx.x * 256 + threadIdx.x;
  if (o < CDIM * C3) {                       // coalesced write, strided read
    int n = o >> 7, k = o & 127;
    qkvT[o] = (__bf16)qkv_w[k * C3 + n];
  } else if (o < CDIM * C3 + CDIM * CDIM) {
    int o2 = o - CDIM * C3;
    int n = o2 >> 7, k = o2 & 127;
    projT[o2] = (__bf16)proj_w[k * CDIM + n];
  } else if (o < CDIM * C3 + CDIM * CDIM + NHEAD * NPAD * NPAD) {
    int t3 = o - (CDIM * C3 + CDIM * CDIM);
    int h = t3 >> 12, r = (t3 >> 6) & 63, c = t3 & 63;
    float v;
    if (c >= NTOK) v = -1e30f;           // softmax mask for padded key columns
    else if (r >= NTOK) v = 0.0f;        // padded query rows: finite, never stored
    else {
      int idx = (r / 7 - c / 7 + 6) * 13 + (r % 7 - c % 7 + 6);
      v = bias_table[idx * NHEAD + h];
    }
    blut[t3] = v;
  }
}

// 512 threads = 8 waves. LDS 63488 B -> 2 blocks/CU -> 16 waves/CU (4/SIMD).
__global__ __launch_bounds__(512, 4) void attn_kernel(
    const float* __restrict__ x, const float* __restrict__ qkv_b,
    const float* __restrict__ proj_b,
    const __bf16* __restrict__ qkvT, const __bf16* __restrict__ projT,
    const float* __restrict__ blut, float* __restrict__ out)
{
  __shared__ __align__(16) char smem[63488];
  __bf16* qs_ = (__bf16*)smem;              // 64*136 elems (17408 B); later aliased as O
  __bf16* ks_ = qs_ + NPAD * QS;            // 17408 B
  __bf16* vT_ = ks_ + NPAD * QS;            // 128*72 elems (18432 B)
  __bf16* Pm_ = vT_ + CDIM * VS;            // 8 waves * 16*40 elems (10240 B)

  const int tid  = threadIdx.x;
  const int wave = tid >> 6;                // 0..7
  const int lane = tid & 63;
  const int l15  = lane & 15;
  const int lg   = lane >> 4;

  const int win = blockIdx.x;
  const int b  = win >> 6;
  const int wh = (win >> 3) & 7;
  const int ww = win & 7;
  const float* xbase = x + (((b * 56) + wh * 7) * 56 + ww * 7) * CDIM;

  // ---- qkv GEMM: wave owns 48 output channels (3 nt tiles), loops all 4 M-tiles ----
  const int nb = wave * 48;
  bf16x8 bq[3][4];
  #pragma unroll
  for (int nt = 0; nt < 3; ++nt)
    #pragma unroll
    for (int kt = 0; kt < 4; ++kt)
      bq[nt][kt] = *(const bf16x8*)(qkvT + (nb + nt * 16 + l15) * CDIM + kt * 32 + lg * 8);

  float qb[3];
  #pragma unroll
  for (int nt = 0; nt < 3; ++nt) qb[nt] = qkv_b[nb + nt * 16 + l15];

  #pragma unroll
  for (int mt = 0; mt < 4; ++mt) {
    const int t = mt * 16 + l15;
    bf16x8 a[4];
    if (t < NTOK) {
      const float* src = xbase + ((t / 7) * 56 + (t % 7)) * CDIM + lg * 8;
      #pragma unroll
      for (int kt = 0; kt < 4; ++kt) {
        f32x4 x0 = *(const f32x4*)(src + kt * 32);
        f32x4 x1 = *(const f32x4*)(src + kt * 32 + 4);
        bf16x8 av;
        av[0] = (__bf16)x0[0]; av[1] = (__bf16)x0[1]; av[2] = (__bf16)x0[2]; av[3] = (__bf16)x0[3];
        av[4] = (__bf16)x1[0]; av[5] = (__bf16)x1[1]; av[6] = (__bf16)x1[2]; av[7] = (__bf16)x1[3];
        a[kt] = av;
      }
    } else {
      #pragma unroll
      for (int kt = 0; kt < 4; ++kt)
        #pragma unroll
        for (int q2 = 0; q2 < 8; ++q2) a[kt][q2] = (__bf16)0.0f;
    }
    f32x4 acc[3];
    #pragma unroll
    for (int nt = 0; nt < 3; ++nt) { acc[nt][0]=0.f; acc[nt][1]=0.f; acc[nt][2]=0.f; acc[nt][3]=0.f; }
    #pragma unroll
    for (int nt = 0; nt < 3; ++nt)
      #pragma unroll
      for (int kt = 0; kt < 4; ++kt)
        acc[nt] = __builtin_amdgcn_mfma_f32_16x16x32_bf16(a[kt], bq[nt][kt], acc[nt], 0, 0, 0);

    const int r0 = mt * 16 + lg * 4;
    #pragma unroll
    for (int nt = 0; nt < 3; ++nt) {
      const int n = nb + nt * 16 + l15;     // tile boundaries are multiples of 16 -> uniform branch
      if (n < CDIM) {                        // q: fold in softmax scale
        #pragma unroll
        for (int i = 0; i < 4; ++i)
          qs_[(r0 + i) * QS + n] = (__bf16)((acc[nt][i] + qb[nt]) * SCALE);
      } else if (n < 2 * CDIM) {
        #pragma unroll
        for (int i = 0; i < 4; ++i)
          ks_[(r0 + i) * QS + (n - CDIM)] = (__bf16)(acc[nt][i] + qb[nt]);
      } else {                               // v transposed: vT[ch][token]
        bf16x4 vv;
        #pragma unroll
        for (int i = 0; i < 4; ++i) vv[i] = (__bf16)(acc[nt][i] + qb[nt]);
        *(bf16x4*)(vT_ + (n - 2 * CDIM) * VS + r0) = vv;
      }
    }
  }
  __syncthreads();

  __bf16* O_ = qs_;  // O aliases qs: head h's waves own q-cols == O-cols h*32..+31, rows partitioned

  // ---- attention: wave = (head, M-half). h = wave&3, rows (wave>>2)*32..+31 ----
  {
    const int h  = wave & 3;
    const int hc = h * HDIM;
    const float* blh = blut + h * 4096;
    __bf16* Pw = Pm_ + wave * 16 * PS;

    bf16x8 bk[4];
    #pragma unroll
    for (int nt = 0; nt < 4; ++nt)
      bk[nt] = *(const bf16x8*)(ks_ + (nt * 16 + l15) * QS + hc + lg * 8);

    #pragma unroll
    for (int mi = 0; mi < 2; ++mi) {
      const int mt = (wave >> 2) * 2 + mi;
      const int m0 = mt * 16;
      bf16x8 aqf = *(const bf16x8*)(qs_ + (m0 + l15) * QS + hc + lg * 8);
      f32x4 s[4];
      #pragma unroll
      for (int nt = 0; nt < 4; ++nt) {
        f32x4 z; z[0]=0.f; z[1]=0.f; z[2]=0.f; z[3]=0.f;
        s[nt] = __builtin_amdgcn_mfma_f32_16x16x32_bf16(aqf, bk[nt], z, 0, 0, 0);
      }
      float p2[4], p3[4];
      #pragma unroll
      for (int i = 0; i < 4; ++i) {
        const int r  = m0 + lg * 4 + i;
        const int lr = lg * 4 + i;
        float v0 = s[0][i] + blh[r * 64 +  0 + l15];
        float v1 = s[1][i] + blh[r * 64 + 16 + l15];
        float v2 = s[2][i] + blh[r * 64 + 32 + l15];
        float v3 = s[3][i] + blh[r * 64 + 48 + l15];
        float mx = fmaxf(fmaxf(v0, v1), fmaxf(v2, v3));
        #pragma unroll
        for (int off = 1; off < 16; off <<= 1) mx = fmaxf(mx, __shfl_xor(mx, off));
        v0 = __expf(v0 - mx); v1 = __expf(v1 - mx);
        v2 = __expf(v2 - mx); v3 = __expf(v3 - mx);
        float sum = v0 + v1 + v2 + v3;
        #pragma unroll
        for (int off = 1; off < 16; off <<= 1) sum += __shfl_xor(sum, off);
        const float inv = 1.0f / sum;
        Pw[lr * PS +      l15] = (__bf16)(v0 * inv);   // chunk 0: cols 0..31
        Pw[lr * PS + 16 + l15] = (__bf16)(v1 * inv);
        p2[i] = v2 * inv; p3[i] = v3 * inv;
      }
      f32x4 o0, o1;
      o0[0]=0.f;o0[1]=0.f;o0[2]=0.f;o0[3]=0.f; o1[0]=0.f;o1[1]=0.f;o1[2]=0.f;o1[3]=0.f;
      {
        bf16x8 ap  = *(const bf16x8*)(Pw + l15 * PS + lg * 8);
        bf16x8 bv0 = *(const bf16x8*)(vT_ + (hc      + l15) * VS + lg * 8);
        bf16x8 bv1 = *(const bf16x8*)(vT_ + (hc + 16 + l15) * VS + lg * 8);
        o0 = __builtin_amdgcn_mfma_f32_16x16x32_bf16(ap, bv0, o0, 0, 0, 0);
        o1 = __builtin_amdgcn_mfma_f32_16x16x32_bf16(ap, bv1, o1, 0, 0, 0);
      }
      // chunk 1: cols 32..63 overwrite same buffer (wave-local, DS in-order)
      #pragma unroll
      for (int i = 0; i < 4; ++i) {
        const int lr = lg * 4 + i;
        Pw[lr * PS +      l15] = (__bf16)p2[i];
        Pw[lr * PS + 16 + l15] = (__bf16)p3[i];
      }
      {
        bf16x8 ap  = *(const bf16x8*)(Pw + l15 * PS + lg * 8);
        bf16x8 bv0 = *(const bf16x8*)(vT_ + (hc      + l15) * VS + 32 + lg * 8);
        bf16x8 bv1 = *(const bf16x8*)(vT_ + (hc + 16 + l15) * VS + 32 + lg * 8);
        o0 = __builtin_amdgcn_mfma_f32_16x16x32_bf16(ap, bv0, o0, 0, 0, 0);
        o1 = __builtin_amdgcn_mfma_f32_16x16x32_bf16(ap, bv1, o1, 0, 0, 0);
      }
      const int r0 = m0 + lg * 4;
      #pragma unroll
      for (int i = 0; i < 4; ++i) {
        O_[(r0 + i) * QS + hc +      l15] = (__bf16)o0[i];
        O_[(r0 + i) * QS + hc + 16 + l15] = (__bf16)o1[i];
      }
    }
  }
  __syncthreads();   // proj reads O rows across waves

  // ---- proj GEMM: wave owns 16 output cols ----
  const int nb2 = wave * 16;
  bf16x8 bp[4];
  #pragma unroll
  for (int kt = 0; kt < 4; ++kt)
    bp[kt] = *(const bf16x8*)(projT + (nb2 + l15) * CDIM + kt * 32 + lg * 8);
  const float pb = proj_b[nb2 + l15];
  float* outw = out + (((b * 56) + wh * 7) * 56 + ww * 7) * CDIM;

  #pragma unroll
  for (int mt = 0; mt < 4; ++mt) {
    bf16x8 ao[4];
    #pragma unroll
    for (int kt = 0; kt < 4; ++kt)
      ao[kt] = *(const bf16x8*)(O_ + (mt * 16 + l15) * QS + kt * 32 + lg * 8);
    f32x4 c0;
    c0[0]=0.f;c0[1]=0.f;c0[2]=0.f;c0[3]=0.f;
    #pragma unroll
    for (int kt = 0; kt < 4; ++kt)
      c0 = __builtin_amdgcn_mfma_f32_16x16x32_bf16(ao[kt], bp[kt], c0, 0, 0, 0);
    #pragma unroll
    for (int i = 0; i < 4; ++i) {
      const int r = mt * 16 + lg * 4 + i;
      if (r < NTOK) {
        float* po = outw + ((r / 7) * 56 + (r % 7)) * CDIM + nb2;
        po[l15] = c0[i] + pb;
      }
    }
  }
}

extern "C" void kernel_launch(void* const* d_in, const int* in_sizes, int n_in,
                              void* d_out, int out_size, void* d_ws, size_t ws_size,
                              hipStream_t stream) {
  const float* x          = (const float*)d_in[0];
  const float* qkv_w      = (const float*)d_in[1];
  const float* qkv_b      = (const float*)d_in[2];
  const float* proj_w     = (const float*)d_in[3];
  const float* proj_b     = (const float*)d_in[4];
  const float* bias_table = (const float*)d_in[5];

  __bf16* qkvT  = (__bf16*)d_ws;
  __bf16* projT = qkvT + C3 * CDIM;
  float*  blut  = (float*)((char*)d_ws + 131072);
  float*  out   = (float*)d_out;

  hipLaunchKernelGGL(prep_kernel, dim3(320), dim3(256), 0, stream,
                     qkv_w, proj_w, bias_table, qkvT, projT, blut);
  hipLaunchKernelGGL(attn_kernel, dim3(4096), dim3(512), 0, stream,
                     x, qkv_b, proj_b, qkvT, projT, blut, out);
}

// Round 3
// 274.492 us; speedup vs baseline: 1.2634x; 1.2634x over previous
//
#include <hip/hip_runtime.h>
#include <hip/hip_bf16.h>

#define NTOK 49
#define NPAD 64
#define CDIM 128
#define C3   384
#define NHEAD 4
#define HDIM 32
#define SCALE 0.17677669529663687f

#define QS 136   // q/k row stride (elems): 272 B rows, bank offset 4 mod 32
#define VS 72    // vT row stride
#define PS 40    // per-wave P row stride (32-col chunks)

typedef __attribute__((ext_vector_type(8))) __bf16 bf16x8;
typedef __attribute__((ext_vector_type(4))) __bf16 bf16x4;
typedef __attribute__((ext_vector_type(4))) float f32x4;

#define PIN(v) asm volatile("" : "+v"(v))   // block load-rematerialization

// ws layout (bytes):
//   qkvT  __bf16[384][128]  @ 0        (98304 B)   qkvT[n][k] = qkv_w[k][n]
//   projT __bf16[128][128]  @ 98304    (32768 B)
//   blut  float [4][64][64] @ 131072   (65536 B)   rel-bias LUT, col>=49 -> -1e30

__global__ __launch_bounds__(256) void prep_kernel(
    const float* __restrict__ qkv_w, const float* __restrict__ proj_w,
    const float* __restrict__ bias_table,
    __bf16* __restrict__ qkvT, __bf16* __restrict__ projT, float* __restrict__ blut)
{
  int o = blockIdx.x * 256 + threadIdx.x;
  if (o < CDIM * C3) {
    int n = o >> 7, k = o & 127;
    qkvT[o] = (__bf16)qkv_w[k * C3 + n];
  } else if (o < CDIM * C3 + CDIM * CDIM) {
    int o2 = o - CDIM * C3;
    int n = o2 >> 7, k = o2 & 127;
    projT[o2] = (__bf16)proj_w[k * CDIM + n];
  } else if (o < CDIM * C3 + CDIM * CDIM + NHEAD * NPAD * NPAD) {
    int t3 = o - (CDIM * C3 + CDIM * CDIM);
    int h = t3 >> 12, r = (t3 >> 6) & 63, c = t3 & 63;
    float v;
    if (c >= NTOK) v = -1e30f;           // softmax mask for padded key columns
    else if (r >= NTOK) v = 0.0f;        // padded query rows: finite, never stored
    else {
      int idx = (r / 7 - c / 7 + 6) * 13 + (r % 7 - c % 7 + 6);
      v = bias_table[idx * NHEAD + h];
    }
    blut[t3] = v;
  }
}

// 512 threads = 8 waves. LDS 78336 B -> 2 blocks/CU -> 16 waves/CU (4/SIMD).
__global__ __launch_bounds__(512, 4) void attn_kernel(
    const float* __restrict__ x, const float* __restrict__ qkv_b,
    const float* __restrict__ proj_b,
    const __bf16* __restrict__ qkvT, const __bf16* __restrict__ projT,
    const float* __restrict__ blut, float* __restrict__ out)
{
  __shared__ __align__(16) char smem[78336];
  __bf16* qs_ = (__bf16*)smem;              // 64*136 (17408 B); later aliased as O
  __bf16* ks_ = qs_ + NPAD * QS;            // 17408 B
  __bf16* vT_ = ks_ + NPAD * QS;            // 128*72 (18432 B)
  char*   un_ = (char*)(vT_ + CDIM * VS);   // union region (25088 B):
  float*  xs_f = (float*)un_;               //   phase 0/1: x stage [49][128] f32, swizzled
  __bf16* Pm_  = (__bf16*)un_;              //   phase 2:   8 waves * 16*40 bf16

  const int tid  = threadIdx.x;
  const int wave = tid >> 6;                // 0..7
  const int lane = tid & 63;
  const int l15  = lane & 15;
  const int lg   = lane >> 4;

  const int win = blockIdx.x;
  const int b  = win >> 6;
  const int wh = (win >> 3) & 7;
  const int ww = win & 7;
  const float* xbase = x + (((b * 56) + wh * 7) * 56 + ww * 7) * CDIM;

  // ---- phase 0: stage x window (49 rows x 512 B) into LDS, 16B chunks ----
  // LDS chunk (r, c') holds global chunk (r, c' ^ (r & 7))  [bank-spread swizzle]
  #pragma unroll
  for (int p = 0; p < 4; ++p) {
    int L = p * 512 + tid;                  // 1568 chunks total
    if (L < 1568) {
      int r = L >> 5, cp = L & 31;
      int gc = cp ^ (r & 7);
      const float* gsrc = xbase + ((r / 7) * 56 + (r % 7)) * CDIM + gc * 4;
      *(f32x4*)(xs_f + L * 4) = *(const f32x4*)gsrc;
    }
  }

  // ---- weight B-fragments for qkv GEMM (48 channels per wave), pinned ----
  const int nb = wave * 48;
  bf16x8 bq[3][4];
  #pragma unroll
  for (int nt = 0; nt < 3; ++nt)
    #pragma unroll
    for (int kt = 0; kt < 4; ++kt) {
      bq[nt][kt] = *(const bf16x8*)(qkvT + (nb + nt * 16 + l15) * CDIM + kt * 32 + lg * 8);
      PIN(bq[nt][kt]);
    }
  float qb[3];
  #pragma unroll
  for (int nt = 0; nt < 3; ++nt) qb[nt] = qkv_b[nb + nt * 16 + l15];

  __syncthreads();   // xs ready

  // ---- phase 1: qkv GEMM. A from LDS x-stage, B pinned in regs ----
  #pragma unroll 1
  for (int mt = 0; mt < 4; ++mt) {
    const int t = mt * 16 + l15;
    bf16x8 a[4];
    if (t < NTOK) {
      const int tb = t * 128;
      const int s7 = t & 7;
      #pragma unroll
      for (int kt = 0; kt < 4; ++kt) {
        const int c0 = (kt * 8 + lg * 2) ^ s7;
        const int c1 = (kt * 8 + lg * 2 + 1) ^ s7;
        f32x4 x0 = *(const f32x4*)(xs_f + tb + c0 * 4);
        f32x4 x1 = *(const f32x4*)(xs_f + tb + c1 * 4);
        bf16x8 av;
        av[0] = (__bf16)x0[0]; av[1] = (__bf16)x0[1]; av[2] = (__bf16)x0[2]; av[3] = (__bf16)x0[3];
        av[4] = (__bf16)x1[0]; av[5] = (__bf16)x1[1]; av[6] = (__bf16)x1[2]; av[7] = (__bf16)x1[3];
        a[kt] = av;
      }
    } else {
      #pragma unroll
      for (int kt = 0; kt < 4; ++kt)
        #pragma unroll
        for (int q2 = 0; q2 < 8; ++q2) a[kt][q2] = (__bf16)0.0f;
    }
    f32x4 acc[3];
    #pragma unroll
    for (int nt = 0; nt < 3; ++nt) { acc[nt][0]=0.f; acc[nt][1]=0.f; acc[nt][2]=0.f; acc[nt][3]=0.f; }
    #pragma unroll
    for (int nt = 0; nt < 3; ++nt)
      #pragma unroll
      for (int kt = 0; kt < 4; ++kt)
        acc[nt] = __builtin_amdgcn_mfma_f32_16x16x32_bf16(a[kt], bq[nt][kt], acc[nt], 0, 0, 0);

    const int r0 = mt * 16 + lg * 4;
    #pragma unroll
    for (int nt = 0; nt < 3; ++nt) {
      const int n = nb + nt * 16 + l15;     // tile boundaries multiple of 16 -> uniform branch
      if (n < CDIM) {                        // q: fold in softmax scale
        #pragma unroll
        for (int i = 0; i < 4; ++i)
          qs_[(r0 + i) * QS + n] = (__bf16)((acc[nt][i] + qb[nt]) * SCALE);
      } else if (n < 2 * CDIM) {
        #pragma unroll
        for (int i = 0; i < 4; ++i)
          ks_[(r0 + i) * QS + (n - CDIM)] = (__bf16)(acc[nt][i] + qb[nt]);
      } else {                               // v transposed: vT[ch][token]
        bf16x4 vv;
        #pragma unroll
        for (int i = 0; i < 4; ++i) vv[i] = (__bf16)(acc[nt][i] + qb[nt]);
        *(bf16x4*)(vT_ + (n - 2 * CDIM) * VS + r0) = vv;
      }
    }
  }
  __syncthreads();   // q/k/v ready; xs dead, union region becomes P

  __bf16* O_ = qs_;  // O aliases qs: wave reads exactly the (rows x cols) it overwrites

  // ---- phase 2: attention. wave = (head = wave&3, M-half = wave>>2) ----
  {
    const int h  = wave & 3;
    const int hc = h * HDIM;
    const float* blh = blut + h * 4096;
    __bf16* Pw = Pm_ + wave * 16 * PS;

    bf16x8 bk[4];
    #pragma unroll
    for (int nt = 0; nt < 4; ++nt)
      bk[nt] = *(const bf16x8*)(ks_ + (nt * 16 + l15) * QS + hc + lg * 8);

    #pragma unroll
    for (int mi = 0; mi < 2; ++mi) {
      const int mt = (wave >> 2) * 2 + mi;
      const int m0 = mt * 16;

      float bias[4][4];                      // prefetch: latency hides under MFMAs
      #pragma unroll
      for (int i = 0; i < 4; ++i) {
        const int r = m0 + lg * 4 + i;
        #pragma unroll
        for (int c = 0; c < 4; ++c) bias[i][c] = blh[r * 64 + c * 16 + l15];
      }

      bf16x8 aqf = *(const bf16x8*)(qs_ + (m0 + l15) * QS + hc + lg * 8);
      f32x4 s[4];
      #pragma unroll
      for (int nt = 0; nt < 4; ++nt) {
        f32x4 z; z[0]=0.f; z[1]=0.f; z[2]=0.f; z[3]=0.f;
        s[nt] = __builtin_amdgcn_mfma_f32_16x16x32_bf16(aqf, bk[nt], z, 0, 0, 0);
      }
      float p2[4], p3[4];
      #pragma unroll
      for (int i = 0; i < 4; ++i) {
        const int lr = lg * 4 + i;
        float v0 = s[0][i] + bias[i][0];
        float v1 = s[1][i] + bias[i][1];
        float v2 = s[2][i] + bias[i][2];
        float v3 = s[3][i] + bias[i][3];
        float mx = fmaxf(fmaxf(v0, v1), fmaxf(v2, v3));
        #pragma unroll
        for (int off = 1; off < 16; off <<= 1) mx = fmaxf(mx, __shfl_xor(mx, off));
        v0 = __expf(v0 - mx); v1 = __expf(v1 - mx);
        v2 = __expf(v2 - mx); v3 = __expf(v3 - mx);
        float sum = v0 + v1 + v2 + v3;
        #pragma unroll
        for (int off = 1; off < 16; off <<= 1) sum += __shfl_xor(sum, off);
        const float inv = 1.0f / sum;
        Pw[lr * PS +      l15] = (__bf16)(v0 * inv);   // chunk 0: cols 0..31
        Pw[lr * PS + 16 + l15] = (__bf16)(v1 * inv);
        p2[i] = v2 * inv; p3[i] = v3 * inv;
      }
      f32x4 o0, o1;
      o0[0]=0.f;o0[1]=0.f;o0[2]=0.f;o0[3]=0.f; o1[0]=0.f;o1[1]=0.f;o1[2]=0.f;o1[3]=0.f;
      {
        bf16x8 ap  = *(const bf16x8*)(Pw + l15 * PS + lg * 8);
        bf16x8 bv0 = *(const bf16x8*)(vT_ + (hc      + l15) * VS + lg * 8);
        bf16x8 bv1 = *(const bf16x8*)(vT_ + (hc + 16 + l15) * VS + lg * 8);
        o0 = __builtin_amdgcn_mfma_f32_16x16x32_bf16(ap, bv0, o0, 0, 0, 0);
        o1 = __builtin_amdgcn_mfma_f32_16x16x32_bf16(ap, bv1, o1, 0, 0, 0);
      }
      #pragma unroll
      for (int i = 0; i < 4; ++i) {          // chunk 1: cols 32..63 (wave-local, DS in-order)
        const int lr = lg * 4 + i;
        Pw[lr * PS +      l15] = (__bf16)p2[i];
        Pw[lr * PS + 16 + l15] = (__bf16)p3[i];
      }
      {
        bf16x8 ap  = *(const bf16x8*)(Pw + l15 * PS + lg * 8);
        bf16x8 bv0 = *(const bf16x8*)(vT_ + (hc      + l15) * VS + 32 + lg * 8);
        bf16x8 bv1 = *(const bf16x8*)(vT_ + (hc + 16 + l15) * VS + 32 + lg * 8);
        o0 = __builtin_amdgcn_mfma_f32_16x16x32_bf16(ap, bv0, o0, 0, 0, 0);
        o1 = __builtin_amdgcn_mfma_f32_16x16x32_bf16(ap, bv1, o1, 0, 0, 0);
      }
      const int r0 = m0 + lg * 4;
      #pragma unroll
      for (int i = 0; i < 4; ++i) {
        O_[(r0 + i) * QS + hc +      l15] = (__bf16)o0[i];
        O_[(r0 + i) * QS + hc + 16 + l15] = (__bf16)o1[i];
      }
    }
  }
  __syncthreads();   // proj reads O rows across waves

  // ---- phase 3: proj GEMM, wave owns 16 output cols ----
  const int nb2 = wave * 16;
  bf16x8 bp[4];
  #pragma unroll
  for (int kt = 0; kt < 4; ++kt) {
    bp[kt] = *(const bf16x8*)(projT + (nb2 + l15) * CDIM + kt * 32 + lg * 8);
    PIN(bp[kt]);
  }
  const float pb = proj_b[nb2 + l15];
  float* outw = out + (((b * 56) + wh * 7) * 56 + ww * 7) * CDIM;

  #pragma unroll
  for (int mt = 0; mt < 4; ++mt) {
    bf16x8 ao[4];
    #pragma unroll
    for (int kt = 0; kt < 4; ++kt)
      ao[kt] = *(const bf16x8*)(O_ + (mt * 16 + l15) * QS + kt * 32 + lg * 8);
    f32x4 c0;
    c0[0]=0.f;c0[1]=0.f;c0[2]=0.f;c0[3]=0.f;
    #pragma unroll
    for (int kt = 0; kt < 4; ++kt)
      c0 = __builtin_amdgcn_mfma_f32_16x16x32_bf16(ao[kt], bp[kt], c0, 0, 0, 0);
    #pragma unroll
    for (int i = 0; i < 4; ++i) {
      const int r = mt * 16 + lg * 4 + i;
      if (r < NTOK) {
        float* po = outw + ((r / 7) * 56 + (r % 7)) * CDIM + nb2;
        po[l15] = c0[i] + pb;
      }
    }
  }
}

extern "C" void kernel_launch(void* const* d_in, const int* in_sizes, int n_in,
                              void* d_out, int out_size, void* d_ws, size_t ws_size,
                              hipStream_t stream) {
  const float* x          = (const float*)d_in[0];
  const float* qkv_w      = (const float*)d_in[1];
  const float* qkv_b      = (const float*)d_in[2];
  const float* proj_w     = (const float*)d_in[3];
  const float* proj_b     = (const float*)d_in[4];
  const float* bias_table = (const float*)d_in[5];

  __bf16* qkvT  = (__bf16*)d_ws;
  __bf16* projT = qkvT + C3 * CDIM;
  float*  blut  = (float*)((char*)d_ws + 131072);
  float*  out   = (float*)d_out;

  hipLaunchKernelGGL(prep_kernel, dim3(320), dim3(256), 0, stream,
                     qkv_w, proj_w, bias_table, qkvT, projT, blut);
  hipLaunchKernelGGL(attn_kernel, dim3(4096), dim3(512), 0, stream,
                     x, qkv_b, proj_b, qkvT, projT, blut, out);
}

// Round 4
// 267.259 us; speedup vs baseline: 1.2976x; 1.0271x over previous
//
#include <hip/hip_runtime.h>
#include <hip/hip_bf16.h>

#define NTOK 49
#define NPAD 64
#define CDIM 128
#define C3   384
#define NHEAD 4
#define HDIM 32
#define SCALE 0.17677669529663687f

#define QS 136   // q/k/xa row stride (elems): 272 B rows, bank offset 4 mod 32
#define VS 72    // vT row stride
#define PS 72    // per-wave P row stride (both 32-col chunks side by side)

typedef __attribute__((ext_vector_type(8))) __bf16 bf16x8;
typedef __attribute__((ext_vector_type(4))) __bf16 bf16x4;
typedef __attribute__((ext_vector_type(4))) float f32x4;

#define PIN(v) asm volatile("" : "+v"(v))   // block load-rematerialization / sinking

// ws layout (bytes):
//   qkvT  __bf16[384][128]  @ 0        (98304 B)  qkvT[n][k] = qkv_w[k][n]; q rows pre-scaled
//   projT __bf16[128][128]  @ 98304    (32768 B)
//   blut  float [4][64][64] @ 131072   (65536 B)  rel-bias LUT, col>=49 -> -1e30

__global__ __launch_bounds__(256) void prep_kernel(
    const float* __restrict__ qkv_w, const float* __restrict__ proj_w,
    const float* __restrict__ bias_table,
    __bf16* __restrict__ qkvT, __bf16* __restrict__ projT, float* __restrict__ blut)
{
  int o = blockIdx.x * 256 + threadIdx.x;
  if (o < CDIM * C3) {
    int n = o >> 7, k = o & 127;
    float v = qkv_w[k * C3 + n];
    if (n < CDIM) v *= SCALE;              // fold softmax scale into q weights
    qkvT[o] = (__bf16)v;
  } else if (o < CDIM * C3 + CDIM * CDIM) {
    int o2 = o - CDIM * C3;
    int n = o2 >> 7, k = o2 & 127;
    projT[o2] = (__bf16)proj_w[k * CDIM + n];
  } else if (o < CDIM * C3 + CDIM * CDIM + NHEAD * NPAD * NPAD) {
    int t3 = o - (CDIM * C3 + CDIM * CDIM);
    int h = t3 >> 12, r = (t3 >> 6) & 63, c = t3 & 63;
    float v;
    if (c >= NTOK) v = -1e30f;           // softmax mask for padded key columns
    else if (r >= NTOK) v = 0.0f;        // padded query rows: finite, never stored
    else {
      int idx = (r / 7 - c / 7 + 6) * 13 + (r % 7 - c % 7 + 6);
      v = bias_table[idx * NHEAD + h];
    }
    blut[t3] = v;
  }
}

// 512 threads = 8 waves. LDS 71680 B -> 2 blocks/CU -> 16 waves/CU (4/SIMD).
__global__ __launch_bounds__(512, 4) void attn_kernel(
    const float* __restrict__ x, const float* __restrict__ qkv_b,
    const float* __restrict__ proj_b,
    const __bf16* __restrict__ qkvT, const __bf16* __restrict__ projT,
    const float* __restrict__ blut, float* __restrict__ out)
{
  __shared__ __align__(16) char smem[71680];
  __bf16* qs_ = (__bf16*)smem;              // 64*136 (17408 B); later aliased as O
  __bf16* ks_ = qs_ + NPAD * QS;            // 17408 B
  __bf16* vT_ = ks_ + NPAD * QS;            // 128*72 (18432 B)
  char*   un_ = (char*)(vT_ + CDIM * VS);   // union (18432 B):
  __bf16* xa_ = (__bf16*)un_;               //   phase 0/1: x stage bf16 [64][136], A-layout
  __bf16* Pm_ = (__bf16*)un_;               //   phase 2:   8 waves * [16][72]

  const int tid  = threadIdx.x;
  const int wave = tid >> 6;                // 0..7
  const int lane = tid & 63;
  const int l15  = lane & 15;
  const int lg   = lane >> 4;

  const int win = blockIdx.x;
  const int b  = win >> 6;
  const int wh = (win >> 3) & 7;
  const int ww = win & 7;
  const float* xbase = x + (((b * 56) + wh * 7) * 56 + ww * 7) * CDIM;

  // ---- phase 0: stage x window into LDS as bf16, A-fragment layout; convert ONCE ----
  #pragma unroll
  for (int p = 0; p < 2; ++p) {
    int L = p * 512 + tid;                  // 1024 chunks of 8 elems (rows 49..63 zeroed)
    int r = L >> 4, c = L & 15;
    bf16x8 v8;
    if (r < NTOK) {
      const float* g = xbase + ((r / 7) * 56 + (r % 7)) * CDIM + c * 8;
      f32x4 x0 = *(const f32x4*)g;
      f32x4 x1 = *(const f32x4*)(g + 4);
      v8[0] = (__bf16)x0[0]; v8[1] = (__bf16)x0[1]; v8[2] = (__bf16)x0[2]; v8[3] = (__bf16)x0[3];
      v8[4] = (__bf16)x1[0]; v8[5] = (__bf16)x1[1]; v8[6] = (__bf16)x1[2]; v8[7] = (__bf16)x1[3];
    } else {
      #pragma unroll
      for (int q2 = 0; q2 < 8; ++q2) v8[q2] = (__bf16)0.0f;
    }
    *(bf16x8*)(xa_ + r * QS + c * 8) = v8;
  }

  // ---- weight B-fragments for qkv GEMM (48 channels per wave), pinned ----
  const int nb = wave * 48;
  bf16x8 bq[3][4];
  #pragma unroll
  for (int nt = 0; nt < 3; ++nt)
    #pragma unroll
    for (int kt = 0; kt < 4; ++kt) {
      bq[nt][kt] = *(const bf16x8*)(qkvT + (nb + nt * 16 + l15) * CDIM + kt * 32 + lg * 8);
      PIN(bq[nt][kt]);
    }
  float qb[3];
  #pragma unroll
  for (int nt = 0; nt < 3; ++nt) {
    qb[nt] = qkv_b[nb + nt * 16 + l15];
    if (nb + nt * 16 < CDIM) qb[nt] *= SCALE;   // match pre-scaled q weights
  }

  __syncthreads();   // xa ready

  // ---- phase 1: qkv GEMM. A = one ds_read_b128, B pinned in regs ----
  #pragma unroll 2
  for (int mt = 0; mt < 4; ++mt) {
    bf16x8 a[4];
    #pragma unroll
    for (int kt = 0; kt < 4; ++kt)
      a[kt] = *(const bf16x8*)(xa_ + (mt * 16 + l15) * QS + kt * 32 + lg * 8);

    f32x4 acc[3];
    #pragma unroll
    for (int nt = 0; nt < 3; ++nt) { acc[nt][0]=0.f; acc[nt][1]=0.f; acc[nt][2]=0.f; acc[nt][3]=0.f; }
    #pragma unroll
    for (int nt = 0; nt < 3; ++nt)
      #pragma unroll
      for (int kt = 0; kt < 4; ++kt)
        acc[nt] = __builtin_amdgcn_mfma_f32_16x16x32_bf16(a[kt], bq[nt][kt], acc[nt], 0, 0, 0);

    const int r0 = mt * 16 + lg * 4;
    #pragma unroll
    for (int nt = 0; nt < 3; ++nt) {
      const int n = nb + nt * 16 + l15;     // tile boundaries multiple of 16 -> uniform branch
      if (n < CDIM) {                        // q (pre-scaled)
        #pragma unroll
        for (int i = 0; i < 4; ++i)
          qs_[(r0 + i) * QS + n] = (__bf16)(acc[nt][i] + qb[nt]);
      } else if (n < 2 * CDIM) {
        #pragma unroll
        for (int i = 0; i < 4; ++i)
          ks_[(r0 + i) * QS + (n - CDIM)] = (__bf16)(acc[nt][i] + qb[nt]);
      } else {                               // v transposed: vT[ch][token]
        bf16x4 vv;
        #pragma unroll
        for (int i = 0; i < 4; ++i) vv[i] = (__bf16)(acc[nt][i] + qb[nt]);
        *(bf16x4*)(vT_ + (n - 2 * CDIM) * VS + r0) = vv;
      }
    }
  }
  __syncthreads();   // q/k/v ready; xa dead, union region becomes P

  // ---- prefetch proj weights now: latency hides under phase 2 ----
  const int nb2 = wave * 16;
  bf16x8 bp[4];
  #pragma unroll
  for (int kt = 0; kt < 4; ++kt) {
    bp[kt] = *(const bf16x8*)(projT + (nb2 + l15) * CDIM + kt * 32 + lg * 8);
    PIN(bp[kt]);
  }
  const float pb = proj_b[nb2 + l15];

  __bf16* O_ = qs_;  // O aliases qs: wave reads exactly the (rows x cols) it overwrites

  // ---- phase 2: attention. wave = (head = wave&3, M-half = wave>>2) ----
  {
    const int h  = wave & 3;
    const int hc = h * HDIM;
    const float* blh = blut + h * 4096;
    __bf16* Pw = Pm_ + wave * 16 * PS;

    bf16x8 bk[4];
    #pragma unroll
    for (int nt = 0; nt < 4; ++nt)
      bk[nt] = *(const bf16x8*)(ks_ + (nt * 16 + l15) * QS + hc + lg * 8);
    bf16x8 bv[2][2];                         // [n16][kt]
    #pragma unroll
    for (int n16 = 0; n16 < 2; ++n16)
      #pragma unroll
      for (int kt = 0; kt < 2; ++kt)
        bv[n16][kt] = *(const bf16x8*)(vT_ + (hc + n16 * 16 + l15) * VS + kt * 32 + lg * 8);

    #pragma unroll
    for (int mi = 0; mi < 2; ++mi) {
      const int mt = (wave >> 2) * 2 + mi;
      const int m0 = mt * 16;

      float bias[4][4];                      // prefetch: latency hides under MFMAs
      #pragma unroll
      for (int i = 0; i < 4; ++i) {
        const int r = m0 + lg * 4 + i;
        #pragma unroll
        for (int c = 0; c < 4; ++c) bias[i][c] = blh[r * 64 + c * 16 + l15];
      }

      bf16x8 aqf = *(const bf16x8*)(qs_ + (m0 + l15) * QS + hc + lg * 8);
      f32x4 s[4];
      #pragma unroll
      for (int nt = 0; nt < 4; ++nt) {
        f32x4 z; z[0]=0.f; z[1]=0.f; z[2]=0.f; z[3]=0.f;
        s[nt] = __builtin_amdgcn_mfma_f32_16x16x32_bf16(aqf, bk[nt], z, 0, 0, 0);
      }
      // softmax, no max-subtraction (|s|<~8 << 88); P = raw exp, 1/sum deferred to O
      float inv[4];
      #pragma unroll
      for (int i = 0; i < 4; ++i) {
        const int lr = lg * 4 + i;
        float e0 = __expf(s[0][i] + bias[i][0]);
        float e1 = __expf(s[1][i] + bias[i][1]);
        float e2 = __expf(s[2][i] + bias[i][2]);
        float e3 = __expf(s[3][i] + bias[i][3]);
        Pw[lr * PS +      l15] = (__bf16)e0;
        Pw[lr * PS + 16 + l15] = (__bf16)e1;
        Pw[lr * PS + 32 + l15] = (__bf16)e2;
        Pw[lr * PS + 48 + l15] = (__bf16)e3;
        float sum = (e0 + e1) + (e2 + e3);
        #pragma unroll
        for (int off = 1; off < 16; off <<= 1) sum += __shfl_xor(sum, off);
        inv[i] = __builtin_amdgcn_rcpf(sum);   // chain hides under PV MFMAs below
      }
      f32x4 o0, o1;
      o0[0]=0.f;o0[1]=0.f;o0[2]=0.f;o0[3]=0.f; o1[0]=0.f;o1[1]=0.f;o1[2]=0.f;o1[3]=0.f;
      #pragma unroll
      for (int kt = 0; kt < 2; ++kt) {
        bf16x8 ap = *(const bf16x8*)(Pw + l15 * PS + kt * 32 + lg * 8);
        o0 = __builtin_amdgcn_mfma_f32_16x16x32_bf16(ap, bv[0][kt], o0, 0, 0, 0);
        o1 = __builtin_amdgcn_mfma_f32_16x16x32_bf16(ap, bv[1][kt], o1, 0, 0, 0);
      }
      const int r0 = m0 + lg * 4;
      #pragma unroll
      for (int i = 0; i < 4; ++i) {
        O_[(r0 + i) * QS + hc +      l15] = (__bf16)(o0[i] * inv[i]);
        O_[(r0 + i) * QS + hc + 16 + l15] = (__bf16)(o1[i] * inv[i]);
      }
    }
  }
  __syncthreads();   // proj reads O rows across waves

  // ---- phase 3: proj GEMM, wave owns 16 output cols ----
  float* outw = out + (((b * 56) + wh * 7) * 56 + ww * 7) * CDIM;
  #pragma unroll
  for (int mt = 0; mt < 4; ++mt) {
    bf16x8 ao[4];
    #pragma unroll
    for (int kt = 0; kt < 4; ++kt)
      ao[kt] = *(const bf16x8*)(O_ + (mt * 16 + l15) * QS + kt * 32 + lg * 8);
    f32x4 c0;
    c0[0]=0.f;c0[1]=0.f;c0[2]=0.f;c0[3]=0.f;
    #pragma unroll
    for (int kt = 0; kt < 4; ++kt)
      c0 = __builtin_amdgcn_mfma_f32_16x16x32_bf16(ao[kt], bp[kt], c0, 0, 0, 0);
    #pragma unroll
    for (int i = 0; i < 4; ++i) {
      const int r = mt * 16 + lg * 4 + i;
      if (r < NTOK) {
        float* po = outw + ((r / 7) * 56 + (r % 7)) * CDIM + nb2;
        po[l15] = c0[i] + pb;
      }
    }
  }
}

extern "C" void kernel_launch(void* const* d_in, const int* in_sizes, int n_in,
                              void* d_out, int out_size, void* d_ws, size_t ws_size,
                              hipStream_t stream) {
  const float* x          = (const float*)d_in[0];
  const float* qkv_w      = (const float*)d_in[1];
  const float* qkv_b      = (const float*)d_in[2];
  const float* proj_w     = (const float*)d_in[3];
  const float* proj_b     = (const float*)d_in[4];
  const float* bias_table = (const float*)d_in[5];

  __bf16* qkvT  = (__bf16*)d_ws;
  __bf16* projT = qkvT + C3 * CDIM;
  float*  blut  = (float*)((char*)d_ws + 131072);
  float*  out   = (float*)d_out;

  hipLaunchKernelGGL(prep_kernel, dim3(320), dim3(256), 0, stream,
                     qkv_w, proj_w, bias_table, qkvT, projT, blut);
  hipLaunchKernelGGL(attn_kernel, dim3(4096), dim3(512), 0, stream,
                     x, qkv_b, proj_b, qkvT, projT, blut, out);
}